// Round 13
// baseline (303.509 us; speedup 1.0000x reference)
//
#include <hip/hip_runtime.h>

// PostNormBoth: T=256-step recurrence, B=512 chains, H=256.
// R14 = R12 (verified 258us) + ONE isolated change from the failed R13:
//   per-lane weight tables in VGPRs + v_readlane. Lane tau holds
//   wt[tau][0..4] and coef(tau)=1+csv*wdot(tau). 11 readlanes/step
//   (wave-uniform SGPR results) replace the s_wt b128+b32 LDS reads and
//   the 5-reg weight rotation. Weight math is bit-identical to R12
//   (same expf/normalize, same dot association).
// R13's other two changes (batched slot IO via [col][slot] relayout,
// 4x unroll) are REVERTED pending this isolation: R13 failed absmax 0.52
// with all three combined; paper audit clears each individually, so this
// round bisects on hardware. Loop structure, mcol [slot][col] layout,
// per-step retire/admit, t&1 s_acc ping-pong: R12 verbatim.

#define TT 256

typedef __bf16 bf16x8 __attribute__((ext_vector_type(8)));
typedef float  f32x4  __attribute__((ext_vector_type(4)));
typedef float  f32x2  __attribute__((ext_vector_type(2)));

#define C2 2.8853900817779268f   // 2*log2(e)

__device__ __forceinline__ float tanh_pre(float u) {   // tanh with pre-scaled arg
    float e = exp2f(u);
    return 1.f - __fdividef(2.f, e + 1.f);
}

template<int CTRL, int RM>
__device__ __forceinline__ float dpp_add(float v) {
    int t = __builtin_amdgcn_update_dpp(0, __float_as_int(v), CTRL, RM, 0xf, true);
    return v + __int_as_float(t);
}
__device__ __forceinline__ float swap32_add(float v) {
    float a = v, b = v;
    asm("v_permlane32_swap_b32 %0, %1" : "+v"(a), "+v"(b));
    return a + b;
}
__device__ __forceinline__ float swap16_add(float v) {
    float a = v, b = v;
    asm("v_permlane16_swap_b32 %0, %1" : "+v"(a), "+v"(b));
    return a + b;
}
__device__ __forceinline__ float rl(float v, int l) {   // uniform readlane
    return __int_as_float(__builtin_amdgcn_readlane(__float_as_int(v), l));
}

// ---- dynamic LDS layout (bytes) ----
// s_mem [2][64][256] f32 :      0  (131072)
// s_x   [2][256]     f32 : 131072  (2048)
// s_v   [2][288]     bf16: 133120  (1152)
// s_acc [2][2][2]    f32 : 134272  (32)
// s_oacc[20]         f32 : 134304  (80)
#define SMEM_BYTES 134384

__global__ __launch_bounds__(512, 2)
void postnorm_kernel(const float* __restrict__ x,
                     const float* __restrict__ W_embed,
                     const float* __restrict__ b_embed,
                     const float* __restrict__ W_update,
                     const float* __restrict__ b_update,
                     const float* __restrict__ gamma,
                     const float* __restrict__ beta,
                     const float* __restrict__ W_out,
                     const float* __restrict__ b_out,
                     const float* __restrict__ ctx_s,
                     float* __restrict__ out)
{
    extern __shared__ __align__(16) char smem[];
    float*  s_mem  = (float*)(smem);
    float*  s_x    = (float*)(smem + 131072);
    __bf16* s_v    = (__bf16*)(smem + 133120);
    float*  s_acc  = (float*)(smem + 134272);
    float*  s_oacc = (float*)(smem + 134304);

    const int tid  = threadIdx.x;
    const int wave = tid >> 6;       // wave w owns W rows [32w,32w+32)
    const int lane = tid & 63;
    const int bn   = lane & 15;      // MFMA col
    const int quad = lane >> 4;
    const int r0   = blockIdx.x * 2;

    // ownership: this lane's accumulators hold y[i_own] for row `row`
    const int b     = bn >> 1;
    const int row   = bn & 1;
    const int i_own = wave * 32 + (b >> 2) * 16 + quad * 4 + (b & 3);

    // ---- init ----
    {   f32x4 z = {0.f, 0.f, 0.f, 0.f};
        f32x4* p = (f32x4*)s_mem;
        #pragma unroll
        for (int k = 0; k < 16; ++k) p[tid + k * 512] = z;
    }
    s_x[tid] = x[(r0 + (tid >> 8)) * TT + (tid & 255)];
    if (tid < 8)  s_acc[tid] = 0.f;
    if (tid < 20) s_oacc[tid] = 0.f;

    const float csv = 1.f / (1.f + expf(-ctx_s[0]));

    // ---- per-lane weight tables (lane tau holds wt[tau][k], coef(tau)) ----
    float wtab0, wtab1, wtab2, wtab3, wtab4, ctab;
    {
        float wv[5], wn[5]; float sa = 0.f, sb = 0.f;
        const int p1 = (lane + 1) & 63;
        #pragma unroll
        for (int k = 0; k < 5; ++k) {
            int ia = (lane + k - 2) & 63;            // wrapped index
            float da = (float)ia - (float)lane;      // delta AFTER wrap
            wv[k] = expf(-(da * da) * 0.125f);  sa += wv[k];   // TAU=8
            int ib = (p1 + k - 2) & 63;
            float db = (float)ib - (float)p1;
            wn[k] = expf(-(db * db) * 0.125f);  sb += wn[k];
        }
        float ra = 1.f / sa, rb = 1.f / sb;
        #pragma unroll
        for (int k = 0; k < 5; ++k) { wv[k] *= ra; wn[k] *= rb; }
        wtab0 = wv[0]; wtab1 = wv[1]; wtab2 = wv[2]; wtab3 = wv[3]; wtab4 = wv[4];
        float wdot = (wn[0] * wv[1] + wn[1] * wv[2]) + (wn[2] * wv[3] + wn[3] * wv[4]);
        ctab = fmaf(csv, wdot, 1.f);
    }

    // per-owned-i params (pre-scaled for exp2 tanh)
    const float we2 = W_embed[i_own] * C2;
    const float be2 = b_embed[i_own] * C2;
    const float bu2 = b_update[i_own] * C2;
    const float gm  = gamma[i_own];
    const float btt = beta[i_own];

    // ---- W_update -> bf16 MFMA A-fragments ----
    bf16x8 wfa[2][8];
    #pragma unroll
    for (int mt = 0; mt < 2; ++mt) {
        #pragma unroll
        for (int kt = 0; kt < 8; ++kt) {
            const float* wp = W_update + (wave * 32 + mt * 16 + bn) * 256
                                       + kt * 32 + quad * 8;
            f32x4 a = *(const f32x4*)wp;
            f32x4 bb = *(const f32x4*)(wp + 4);
            bf16x8 f;
            f[0] = (__bf16)a[0];  f[1] = (__bf16)a[1];
            f[2] = (__bf16)a[2];  f[3] = (__bf16)a[3];
            f[4] = (__bf16)bb[0]; f[5] = (__bf16)bb[1];
            f[6] = (__bf16)bb[2]; f[7] = (__bf16)bb[3];
            wfa[mt][kt] = f;
        }
    }

    __syncthreads();
    {   // v(t=0): memory==0, h==0 -> v = inp
        float inp0 = tanh_pre(fmaf(s_x[row * 256], we2, be2));
        s_v[row * 288 + i_own] = (__bf16)inp0;
    }
    __syncthreads();

    float hn = 0.f;
    // register window: slots (t-2..t+2) mod 64 of memory column (row,i_own)
    float w0 = 0.f, w1 = 0.f, w2 = 0.f, w3 = 0.f, w4 = 0.f;
    float nf = 0.f;                              // admit slot 3 (zero-init)
    float xn = s_x[row * 256 + 1];               // x[t+1] for own row
    float* mcol = s_mem + (row << 14) + i_own;
    const __bf16* vsrc = s_v + row * 288 + quad * 8;

    #pragma unroll 1
    for (int t = 0; t < TT; ++t) {
        const int rb = t & 1, wb = rb ^ 1;
        const int ta = t & 63, tn1 = (t + 1) & 63;

        // weights via readlane (uniform SGPRs; no LDS, no rotation regs)
        const float nw0 = rl(wtab0, tn1), nw1 = rl(wtab1, tn1),
                    nw2 = rl(wtab2, tn1), nw3 = rl(wtab3, tn1),
                    nw4 = rl(wtab4, tn1);
        const float cw0 = rl(wtab0, ta), cw1 = rl(wtab1, ta),
                    cw2 = rl(wtab2, ta), cw3 = rl(wtab3, ta),
                    cw4 = rl(wtab4, ta);
        const float coef = rl(ctab, ta);

        // --- pre-barrier: everything not depending on stats(t) ---
        float inp  = tanh_pre(fmaf(xn, we2, be2));
        float ctxA = ((nw0 * w1 + nw1 * w2) + (nw2 * w3 + nw3 * w4)) + nw4 * nf;
        float base = fmaf(csv, ctxA, inp);

        // --- P1: y = W . v via MFMA; D col bn carries row bn&1 ---
        f32x4 a0a = {0,0,0,0}, a0b = {0,0,0,0}, a1a = {0,0,0,0}, a1b = {0,0,0,0};
        #pragma unroll
        for (int kt = 0; kt < 4; ++kt) {
            bf16x8 bfr0 = *(const bf16x8*)(vsrc + kt * 32);
            bf16x8 bfr1 = *(const bf16x8*)(vsrc + (kt + 4) * 32);
            a0a = __builtin_amdgcn_mfma_f32_16x16x32_bf16(wfa[0][kt],     bfr0, a0a, 0, 0, 0);
            a1a = __builtin_amdgcn_mfma_f32_16x16x32_bf16(wfa[1][kt],     bfr0, a1a, 0, 0, 0);
            a0b = __builtin_amdgcn_mfma_f32_16x16x32_bf16(wfa[0][kt + 4], bfr1, a0b, 0, 0, 0);
            a1b = __builtin_amdgcn_mfma_f32_16x16x32_bf16(wfa[1][kt + 4], bfr1, a1b, 0, 0, 0);
        }

        // --- select owned y from regs: (mt,r) = (b>>2, b&3) ---
        f32x4 y0 = a0a + a0b, y1 = a1a + a1b;
        f32x4 ym = (b & 4) ? y1 : y0;
        float yA = (b & 2) ? ym[2] : ym[0];
        float yB = (b & 2) ? ym[3] : ym[1];
        float ysel = (b & 1) ? yB : yA;

        // --- P2: tanh + all-VALU row-parity reduce (bits 1,2,3,4,5) ---
        float yt = tanh_pre(fmaf(ysel, C2, bu2));
        float s1 = yt, s2 = yt * yt;
        s1 = dpp_add<0x4E,  0xf>(s1);  s2 = dpp_add<0x4E,  0xf>(s2);  // xor2
        s1 = dpp_add<0x124, 0xf>(s1);  s2 = dpp_add<0x124, 0xf>(s2);  // ror:4
        s1 = dpp_add<0x128, 0xf>(s1);  s2 = dpp_add<0x128, 0xf>(s2);  // ror:8
        s1 = swap16_add(s1);           s2 = swap16_add(s2);           // bit4
        s1 = swap32_add(s1);           s2 = swap32_add(s2);           // bit5
        if (lane < 4)
            atomicAdd(&s_acc[rb * 4 + (lane & 1) * 2 + (lane >> 1)],
                      (lane & 2) ? s2 : s1);
        __syncthreads();   // [1] partials summed (also fences vsrc reads)

        // --- P3: finalize = ONE b64 read; then hn -> v (1 fma + cvt) ---
        f32x2 S = *(const f32x2*)(s_acc + rb * 4 + row * 2);
        if (tid < 4) s_acc[wb * 4 + tid] = 0.f;   // reset other buf (dead now)
        float mu   = S[0] * (1.f / 256.f);
        float var  = S[1] * (1.f / 256.f) - mu * mu;
        float rstd = rsqrtf(var + 1e-5f);
        hn = fmaf(yt - mu, rstd * gm, btt);
        float v = fmaf(coef, hn, base);
        s_v[row * 288 + i_own] = (__bf16)v;        // critical write ASAP

        // --- off-chain: window scatter+slide (fused) + retire + prefetch ---
        float rv = fmaf(cw0, hn, w0);
        w0 = fmaf(cw1, hn, w1); w1 = fmaf(cw2, hn, w2);
        w2 = fmaf(cw3, hn, w3); w3 = fmaf(cw4, hn, w4); w4 = nf;
        mcol[((t - 2) & 63) << 8] = rv;            // retire slot t-2
        nf  = mcol[((t + 4) & 63) << 8];           // same-thread col: no hazard
        xn  = s_x[row * 256 + ((t + 2) & 255)];
        __syncthreads();   // [2] v visible
    }

    // --- epilogue: stage hn into s_x to restore tid-order ---
    s_x[row * 256 + i_own] = hn;
    __syncthreads();
    {
        const int n = tid >> 8, i = tid & 255;
        float h = s_x[tid];
        #pragma unroll
        for (int o = 0; o < 10; ++o) {
            float p = h * W_out[o * 256 + i];
            #pragma unroll
            for (int m = 32; m >= 1; m >>= 1) p += __shfl_xor(p, m, 64);
            if (lane == 0) atomicAdd(&s_oacc[n * 10 + o], p);
        }
    }
    __syncthreads();
    if (tid < 20) {
        int nn = tid / 10, o = tid % 10;
        out[(r0 + nn) * 10 + o] = s_oacc[tid] + b_out[o];
    }
}

extern "C" void kernel_launch(void* const* d_in, const int* in_sizes, int n_in,
                              void* d_out, int out_size, void* d_ws, size_t ws_size,
                              hipStream_t stream) {
    const float* x    = (const float*)d_in[0];
    const float* W_e  = (const float*)d_in[1];
    const float* b_e  = (const float*)d_in[2];
    const float* W_u  = (const float*)d_in[3];
    const float* b_u  = (const float*)d_in[4];
    const float* gmm  = (const float*)d_in[5];
    const float* bta  = (const float*)d_in[6];
    const float* W_o  = (const float*)d_in[7];
    const float* b_o  = (const float*)d_in[8];
    const float* cst  = (const float*)d_in[9];
    float* out = (float*)d_out;

    (void)hipFuncSetAttribute(reinterpret_cast<const void*>(postnorm_kernel),
                              hipFuncAttributeMaxDynamicSharedMemorySize,
                              SMEM_BYTES);

    postnorm_kernel<<<dim3(256), dim3(512), SMEM_BYTES, stream>>>(
        x, W_e, b_e, W_u, b_u, gmm, bta, W_o, b_o, cst, out);
}

// Round 15
// 287.266 us; speedup vs baseline: 1.0565x; 1.0565x over previous
//
#include <hip/hip_runtime.h>

// PostNormBoth: T=256-step recurrence, B=512 chains, H=256.
// R16 = R15 RESUBMIT (previous round died to infra: "container failed
// twice", same mode as R5 which passed unchanged on resubmit; code audit
// found no defect). R12 chassis (verified 258.1us) + three per-lane-work
// cuts:
//  (1) variance-channel transpose reduce: lane-bit1 becomes the s1/s2 axis.
//      e = yt[lane^2] (1 DPP mov); bit1=0 lanes carry yt+e, bit1=1 carry
//      yt^2+e^2; ONE 4-level ladder (ror:4, ror:8, permlane16, permlane32;
//      bits 0,1 preserved) reduces BOTH stats. Lanes 0-3 = the 4 atomic
//      writers (row x var), same s_acc mapping as R12. ~26 -> ~13 ops.
//  (2) W_update pre-scaled by 2*log2e in the bf16 A-fragments, and
//      b_update*C2 loaded as the MFMA C-initializer -> yt = tanh_pre(ysel)
//      directly (chain fma deleted).
//  (3) everything else R12 verbatim: s_wt LDS prefetch + reg rotation
//      (R14 proved readlane slower), per-step retire/admit, t&1 s_acc
//      ping-pong, atomic stats, ctx decomposition.

#define TT 256

typedef __bf16 bf16x8 __attribute__((ext_vector_type(8)));
typedef float  f32x4  __attribute__((ext_vector_type(4)));
typedef float  f32x2  __attribute__((ext_vector_type(2)));

#define C2 2.8853900817779268f   // 2*log2(e)

__device__ __forceinline__ float tanh_pre(float u) {   // tanh with pre-scaled arg
    float e = exp2f(u);
    return 1.f - __fdividef(2.f, e + 1.f);
}

template<int CTRL, int RM>
__device__ __forceinline__ float dpp_add(float v) {
    int t = __builtin_amdgcn_update_dpp(0, __float_as_int(v), CTRL, RM, 0xf, true);
    return v + __int_as_float(t);
}
// pure lane^2 permute (quad_perm [2,3,0,1])
__device__ __forceinline__ float dpp_xor2_mov(float v) {
    int t = __builtin_amdgcn_update_dpp(0, __float_as_int(v), 0x4E, 0xf, 0xf, true);
    return __int_as_float(t);
}
__device__ __forceinline__ float swap32_add(float v) {
    float a = v, b = v;
    asm("v_permlane32_swap_b32 %0, %1" : "+v"(a), "+v"(b));
    return a + b;
}
__device__ __forceinline__ float swap16_add(float v) {
    float a = v, b = v;
    asm("v_permlane16_swap_b32 %0, %1" : "+v"(a), "+v"(b));
    return a + b;
}

// ---- dynamic LDS layout (bytes) ----
// s_mem [2][64][256] f32 :      0  (131072)
// s_x   [2][256]     f32 : 131072  (2048)
// s_v   [2][288]     bf16: 133120  (1152)
// s_acc [2][2][2]    f32 : 134272  (32)
// s_wt  [64][8]      f32 : 134304  (2048)
// s_oacc[20]         f32 : 136352  (80)
#define SMEM_BYTES 136432

__global__ __launch_bounds__(512, 2)
void postnorm_kernel(const float* __restrict__ x,
                     const float* __restrict__ W_embed,
                     const float* __restrict__ b_embed,
                     const float* __restrict__ W_update,
                     const float* __restrict__ b_update,
                     const float* __restrict__ gamma,
                     const float* __restrict__ beta,
                     const float* __restrict__ W_out,
                     const float* __restrict__ b_out,
                     const float* __restrict__ ctx_s,
                     float* __restrict__ out)
{
    extern __shared__ __align__(16) char smem[];
    float*  s_mem  = (float*)(smem);
    float*  s_x    = (float*)(smem + 131072);
    __bf16* s_v    = (__bf16*)(smem + 133120);
    float*  s_acc  = (float*)(smem + 134272);
    float*  s_wt   = (float*)(smem + 134304);
    float*  s_oacc = (float*)(smem + 136352);

    const int tid  = threadIdx.x;
    const int wave = tid >> 6;       // wave w owns W rows [32w,32w+32)
    const int lane = tid & 63;
    const int bn   = lane & 15;      // MFMA col
    const int quad = lane >> 4;
    const int r0   = blockIdx.x * 2;

    // ownership: this lane's accumulators hold y[i_own] for row `row`
    const int b     = bn >> 1;
    const int row   = bn & 1;
    const int i_own = wave * 32 + (b >> 2) * 16 + quad * 4 + (b & 3);

    // ---- init ----
    {   f32x4 z = {0.f, 0.f, 0.f, 0.f};
        f32x4* p = (f32x4*)s_mem;
        #pragma unroll
        for (int k = 0; k < 16; ++k) p[tid + k * 512] = z;
    }
    s_x[tid] = x[(r0 + (tid >> 8)) * TT + (tid & 255)];
    if (tid < 8)  s_acc[tid] = 0.f;
    if (tid < 20) s_oacc[tid] = 0.f;

    // weight table: pointer is t&63; row padded to 8 floats
    if (tid < 64) {
        float wv[5]; float ssum = 0.f;
        #pragma unroll
        for (int k = 0; k < 5; ++k) {
            int idx = (tid + k - 2) & 63;            // wrapped index
            float d = (float)idx - (float)tid;       // delta AFTER wrap
            wv[k] = expf(-(d * d) * 0.125f);         // TAU=8
            ssum += wv[k];
        }
        #pragma unroll
        for (int k = 0; k < 5; ++k) s_wt[tid * 8 + k] = wv[k] / ssum;
    }

    const float csv = 1.f / (1.f + expf(-ctx_s[0]));

    // per-owned-i params (embed side pre-scaled for exp2 tanh)
    const float we2 = W_embed[i_own] * C2;
    const float be2 = b_embed[i_own] * C2;
    const float gm  = gamma[i_own];
    const float btt = beta[i_own];

    // MFMA C-initializers: b_update*C2 for this lane's (quad, r) rows,
    // tile mt=0 (a0a chain) and mt=1 (a1a chain); bn-independent.
    f32x4 bu4a = *(const f32x4*)(b_update + wave * 32 + quad * 4);
    f32x4 bu4b = *(const f32x4*)(b_update + wave * 32 + 16 + quad * 4);
    #pragma unroll
    for (int j = 0; j < 4; ++j) { bu4a[j] *= C2; bu4b[j] *= C2; }

    // ---- W_update -> bf16 MFMA A-fragments, PRE-SCALED by C2 ----
    bf16x8 wfa[2][8];
    #pragma unroll
    for (int mt = 0; mt < 2; ++mt) {
        #pragma unroll
        for (int kt = 0; kt < 8; ++kt) {
            const float* wp = W_update + (wave * 32 + mt * 16 + bn) * 256
                                       + kt * 32 + quad * 8;
            f32x4 a = *(const f32x4*)wp;
            f32x4 bb = *(const f32x4*)(wp + 4);
            bf16x8 f;
            f[0] = (__bf16)(a[0] * C2);  f[1] = (__bf16)(a[1] * C2);
            f[2] = (__bf16)(a[2] * C2);  f[3] = (__bf16)(a[3] * C2);
            f[4] = (__bf16)(bb[0] * C2); f[5] = (__bf16)(bb[1] * C2);
            f[6] = (__bf16)(bb[2] * C2); f[7] = (__bf16)(bb[3] * C2);
            wfa[mt][kt] = f;
        }
    }

    __syncthreads();
    {   // v(t=0): memory==0, h==0 -> v = inp
        float inp0 = tanh_pre(fmaf(s_x[row * 256], we2, be2));
        s_v[row * 288 + i_own] = (__bf16)inp0;
    }

    // attention weights for pointer 0 + step-0 prefetches
    float wt0, wt1, wt2, wt3, wt4;
    {   f32x4 wv = *(const f32x4*)(s_wt);
        wt0 = wv[0]; wt1 = wv[1]; wt2 = wv[2]; wt3 = wv[3]; wt4 = s_wt[4];
    }
    f32x4 nw  = *(const f32x4*)(s_wt + 8);       // weights for pointer t+1
    float nw4 = s_wt[8 + 4];
    float xn  = s_x[row * 256 + 1];              // x[t+1] for own row
    float nf  = 0.f;                             // admit slot 3 (zero-init)
    __syncthreads();

    float hn = 0.f;
    // register window: slots (t-2..t+2) mod 64 of memory column (row,i_own)
    float w0 = 0.f, w1 = 0.f, w2 = 0.f, w3 = 0.f, w4 = 0.f;
    float* mcol = s_mem + (row << 14) + i_own;
    const __bf16* vsrc = s_v + row * 288 + quad * 8;

    #pragma unroll 1
    for (int t = 0; t < TT; ++t) {
        const int rb = t & 1, wb = rb ^ 1;

        // --- pre-barrier: everything not depending on stats(t) ---
        float inp  = tanh_pre(fmaf(xn, we2, be2));
        float ctxA = ((nw[0] * w1 + nw[1] * w2) + (nw[2] * w3 + nw[3] * w4))
                   + nw4 * nf;
        float wdot = (nw[0] * wt1 + nw[1] * wt2) + (nw[2] * wt3 + nw[3] * wt4);
        float base = fmaf(csv, ctxA, inp);
        float coef = fmaf(csv, wdot, 1.f);

        // --- P1: u = C2*(W.v + bu) via MFMA (bias in C-init, W pre-scaled) ---
        f32x4 a0a = bu4a, a1a = bu4b;
        f32x4 a0b = {0,0,0,0}, a1b = {0,0,0,0};
        #pragma unroll
        for (int kt = 0; kt < 4; ++kt) {
            bf16x8 bfr0 = *(const bf16x8*)(vsrc + kt * 32);
            bf16x8 bfr1 = *(const bf16x8*)(vsrc + (kt + 4) * 32);
            a0a = __builtin_amdgcn_mfma_f32_16x16x32_bf16(wfa[0][kt],     bfr0, a0a, 0, 0, 0);
            a1a = __builtin_amdgcn_mfma_f32_16x16x32_bf16(wfa[1][kt],     bfr0, a1a, 0, 0, 0);
            a0b = __builtin_amdgcn_mfma_f32_16x16x32_bf16(wfa[0][kt + 4], bfr1, a0b, 0, 0, 0);
            a1b = __builtin_amdgcn_mfma_f32_16x16x32_bf16(wfa[1][kt + 4], bfr1, a1b, 0, 0, 0);
        }

        // --- select owned u from regs: (mt,r) = (b>>2, b&3) ---
        f32x4 y0 = a0a + a0b, y1 = a1a + a1b;
        f32x4 ym = (b & 4) ? y1 : y0;
        float yA = (b & 2) ? ym[2] : ym[0];
        float yB = (b & 2) ? ym[3] : ym[1];
        float ysel = (b & 1) ? yB : yA;

        // --- P2: tanh + variance-channel-transposed reduce ---
        float yt = tanh_pre(ysel);                 // bias already inside
        float e  = dpp_xor2_mov(yt);               // partner (lane^2) yt
        float v0 = yt + e;                         // s1 pair-sum
        float v1 = fmaf(e, e, yt * yt);            // s2 pair-sum
        float s  = ((lane >> 1) & 1) ? v1 : v0;    // bit1 = variance channel
        s = dpp_add<0x124, 0xf>(s);                // ror:4  (bits 2,3 pt1)
        s = dpp_add<0x128, 0xf>(s);                // ror:8  (bits 2,3 pt2)
        s = swap16_add(s);                         // bit4
        s = swap32_add(s);                         // bit5
        // lane (bit0=row, bit1=var) in 0..3 holds its class's wave partial
        if (lane < 4)
            atomicAdd(&s_acc[rb * 4 + (lane & 1) * 2 + (lane >> 1)], s);
        __syncthreads();   // [1] partials summed (also fences vsrc reads)

        // --- P3: finalize = ONE b64 read; then hn -> v (1 fma + cvt) ---
        f32x2 S = *(const f32x2*)(s_acc + rb * 4 + row * 2);
        if (tid < 4) s_acc[wb * 4 + tid] = 0.f;   // reset other buf (dead now)
        float mu   = S[0] * (1.f / 256.f);
        float var  = S[1] * (1.f / 256.f) - mu * mu;
        float rstd = rsqrtf(var + 1e-5f);
        hn = fmaf(yt - mu, rstd * gm, btt);
        float v = fmaf(coef, hn, base);
        s_v[row * 288 + i_own] = (__bf16)v;        // critical write ASAP

        // --- off-chain: window scatter+slide (fused) + retire + prefetch ---
        float rv = fmaf(wt0, hn, w0);
        w0 = fmaf(wt1, hn, w1); w1 = fmaf(wt2, hn, w2);
        w2 = fmaf(wt3, hn, w3); w3 = fmaf(wt4, hn, w4); w4 = nf;
        mcol[((t - 2) & 63) << 8] = rv;            // retire slot t-2
        wt0 = nw[0]; wt1 = nw[1]; wt2 = nw[2]; wt3 = nw[3]; wt4 = nw4;
        nf  = mcol[((t + 4) & 63) << 8];           // same-thread col: no hazard
        {   const float* wp = s_wt + ((t + 2) & 63) * 8;
            nw  = *(const f32x4*)wp;
            nw4 = wp[4];
        }
        xn  = s_x[row * 256 + ((t + 2) & 255)];
        __syncthreads();   // [2] v visible
    }

    // --- epilogue: stage hn into s_x to restore tid-order ---
    s_x[row * 256 + i_own] = hn;
    __syncthreads();
    {
        const int n = tid >> 8, i = tid & 255;
        float h = s_x[tid];
        #pragma unroll
        for (int o = 0; o < 10; ++o) {
            float p = h * W_out[o * 256 + i];
            #pragma unroll
            for (int m = 32; m >= 1; m >>= 1) p += __shfl_xor(p, m, 64);
            if (lane == 0) atomicAdd(&s_oacc[n * 10 + o], p);
        }
    }
    __syncthreads();
    if (tid < 20) {
        int nn = tid / 10, o = tid % 10;
        out[(r0 + nn) * 10 + o] = s_oacc[tid] + b_out[o];
    }
}

extern "C" void kernel_launch(void* const* d_in, const int* in_sizes, int n_in,
                              void* d_out, int out_size, void* d_ws, size_t ws_size,
                              hipStream_t stream) {
    const float* x    = (const float*)d_in[0];
    const float* W_e  = (const float*)d_in[1];
    const float* b_e  = (const float*)d_in[2];
    const float* W_u  = (const float*)d_in[3];
    const float* b_u  = (const float*)d_in[4];
    const float* gmm  = (const float*)d_in[5];
    const float* bta  = (const float*)d_in[6];
    const float* W_o  = (const float*)d_in[7];
    const float* b_o  = (const float*)d_in[8];
    const float* cst  = (const float*)d_in[9];
    float* out = (float*)d_out;

    (void)hipFuncSetAttribute(reinterpret_cast<const void*>(postnorm_kernel),
                              hipFuncAttributeMaxDynamicSharedMemorySize,
                              SMEM_BYTES);

    postnorm_kernel<<<dim3(256), dim3(512), SMEM_BYTES, stream>>>(
        x, W_e, b_e, W_u, b_u, gmm, bta, W_o, b_o, cst, out);
}